// Round 10
// baseline (290.018 us; speedup 1.0000x reference)
//
#include <hip/hip_runtime.h>

#define N_NODES 50000
#define N_EDGES 1600000
#define NPB     16
#define NCH     8     // csr chains per node: chain = e & 7 (400K counters)
#define NCHAIN  16    // fat/thin sub-chains per node: chain = e & 15
#define KSTR    168   // A-tile k-stride in shorts (160 + 8 pad: breaks bank conflict on A-frag ds_read_b128)
#define EPSV    1e-8f

typedef float f32x4 __attribute__((ext_vector_type(4)));
typedef short s16x8 __attribute__((ext_vector_type(8)));

// 4-aligned 16B chunk (frames rows are 36B, only 4B-aligned)
struct f4u { float a, b, c, d; };

__device__ __forceinline__ float sigmoidf_(float x) { return 1.0f / (1.0f + __expf(-x)); }
// f32 -> bf16 bits, round-to-nearest-even
__device__ __forceinline__ short f2bf(float x) {
    unsigned u = __float_as_uint(x);
    unsigned r = (u + 0x7FFFu + ((u >> 16) & 1u)) >> 16;
    return (short)r;
}
__device__ __forceinline__ float bf2f(short h) {
    return __uint_as_float(((unsigned)(unsigned short)h) << 16);
}
// pack two f32 -> one u32 of 2 bf16 (lo = first)
__device__ __forceinline__ unsigned pkbf(float lo, float hi) {
    return (unsigned)(unsigned short)f2bf(lo) | ((unsigned)(unsigned short)f2bf(hi) << 16);
}
__device__ __forceinline__ float bflo(unsigned u) { return __uint_as_float(u << 16); }
__device__ __forceinline__ float bfhi(unsigned u) { return __uint_as_float(u & 0xffff0000u); }

// ---------------------------------------------------------------------------
// W-split kernel: Dekker-split W_so into TRANSPOSED bf16 hi/lo WT[o][k]
// (k-contiguous so each MFMA B-frag is one 16B load), k>=153 zeroed.
// Counter/chain arrays are initialized by hipMemsetAsync (DMA, cheaper than
// a 3125-block kernel).
// ---------------------------------------------------------------------------
__global__ __launch_bounds__(256) void wsplit_kernel(
    const float* __restrict__ W_so, short* __restrict__ WThi, short* __restrict__ WTlo) {
    int i = blockIdx.x * 256 + threadIdx.x;
    if (i >= 128 * 160) return;        // i = o*160 + k
    int o = i / 160, k = i - o * 160;
    float w = (k < 153) ? W_so[k * 128 + o] : 0.0f;
    short hh = f2bf(w);
    WThi[i] = hh;
    WTlo[i] = f2bf(w - bf2f(hh));
}

// ---------------------------------------------------------------------------
// Kernel 1 (CSR8I): interleaved fixed-capacity CSR.
//   slot = atomicAdd(&cnt[r*8+c]) — 400K addresses (fabric law from r6-r9:
//   800K addrs ~free, 50K +30us, 3125 +70us; 400K expected near-free).
//   Payload slot = 32B sector at [r][slot][c] (slot-major interleave), FULLY
//   written (r7 lesson: straddling/partial sectors amplify writes 2x).
//   Node side then reads slot-step s of all 8 chains as ONE 256B contiguous
//   run -> streaming gather, zero dependent hops. Overflow (slot>=cap,
//   Poisson(4) tail, ~2-5% of edges at cap 6-8) -> per-chain linked lists.
// ---------------------------------------------------------------------------
__global__ __launch_bounds__(256) void bucket_csr8i_kernel(
    const int* __restrict__ row,
    const float* __restrict__ frames,
    int* __restrict__ cnt,
    int* __restrict__ head2,
    int* __restrict__ nxt,
    unsigned* __restrict__ pay,
    int cap) {
    int e = blockIdx.x * 256 + threadIdx.x;
    if (e >= N_EDGES) return;
    int r = row[e];
    int c = e & (NCH - 1);
    int slot = atomicAdd(&cnt[r * NCH + c], 1);
    if (slot < cap) {
        const float* f = frames + (size_t)e * 9;
        f4u x = ((const f4u*)f)[0];
        f4u y = ((const f4u*)f)[1];
        float z8 = f[8];
        unsigned* dst = pay + (((size_t)r * cap + slot) * NCH + c) * 8;
        ((uint4*)dst)[0] = make_uint4(pkbf(x.a, x.b), pkbf(x.c, x.d), pkbf(y.a, y.b), pkbf(y.c, y.d));
        ((uint4*)dst)[1] = make_uint4((unsigned)(unsigned short)f2bf(z8), 0u, 0u, 0u);
    } else {
        int prev = atomicExch(&head2[r * NCH + c], e);
        nxt[e] = prev;
    }
}

// Kernel 1 (FAT fallback, r9-proven): bf16 payload + nxt in one 32B sector.
__global__ __launch_bounds__(256) void bucket_fat_kernel(
    const int* __restrict__ row,
    const float* __restrict__ frames,
    int* __restrict__ head,
    unsigned* __restrict__ pay) {
    int e = blockIdx.x * 256 + threadIdx.x;
    if (e >= N_EDGES) return;
    int r = row[e];
    int prev = atomicExch(&head[r * NCHAIN + (e & (NCHAIN - 1))], e);
    const float* f = frames + (size_t)e * 9;
    f4u x = ((const f4u*)f)[0];
    f4u y = ((const f4u*)f)[1];
    float z8 = f[8];
    uint4* dst = (uint4*)(pay + (size_t)e * 8);
    dst[0] = make_uint4(pkbf(x.a, x.b), pkbf(x.c, x.d), pkbf(y.a, y.b), pkbf(y.c, y.d));
    dst[1] = make_uint4((unsigned)(unsigned short)f2bf(z8), (unsigned)prev, 0u, 0u);
}

// Thin fallback (tiny ws): classic separate-nxt bucketing.
__global__ __launch_bounds__(256) void bucket_thin_kernel(
    const int* __restrict__ row,
    int* __restrict__ head,
    int* __restrict__ nxt) {
    int e = blockIdx.x * 256 + threadIdx.x;
    if (e >= N_EDGES) return;
    int r = row[e];
    int prev = atomicExch(&head[r * NCHAIN + (e & (NCHAIN - 1))], e);
    nxt[e] = prev;
}

// ---------------------------------------------------------------------------
// Kernel 2: all per-node algebra. 16 nodes per 256-thread block.
// MODE 2 (csr8i): gather = streamed interleaved slots (lane h: chain h&7,
//   slots s = h>>3, h>>3 + 2, ...), deg from counters, rare overflow chains.
// MODE 1 (fat-bf16): one 32B sector per dependent hop (r9-proven).
// MODE 0 (thin): nxt array + raw f32 frames.
// Default launch bounds: (256,8) clamp spilled twice (r2/r4); occupancy is
// not the lever for this kernel (39% vs 74% gave equal-or-worse time).
// ---------------------------------------------------------------------------
template<int MODE>
__global__ __launch_bounds__(256) void node_kernel(
    const float* __restrict__ s,
    const float* __restrict__ v,
    const unsigned* __restrict__ pay,  // M2: pay slots; M1: pay32; M0 unused
    const float* __restrict__ frames,  // M2 overflow + M0
    const float* __restrict__ W_vd,
    const float* __restrict__ W_vdf,
    const short* __restrict__ WThi,
    const short* __restrict__ WTlo,
    const float* __restrict__ b_so,
    const float* __restrict__ W_vu,
    const float* __restrict__ W_vosf,
    const float* __restrict__ b_vosf,
    const float* __restrict__ W_vuf,
    const int* __restrict__ cnt_or_head, // M2: cnt[N*8]; M0/1: head[N*16]
    const int* __restrict__ head2,       // M2 only: overflow heads[N*8]
    const int* __restrict__ nxt,         // M2: overflow; M0: nxt; M1 unused
    int cap,
    float* __restrict__ out0,
    float* __restrict__ out1)
{
    // AL[0]=A hi, AL[1]=A lo, rows k-strided by KSTR shorts. 10.5 KB.
    // After the K-loop barrier it is dead and sigL[16][128] (8 KB) overlays it.
    __shared__ __align__(16) short AL[2][NPB][KSTR];
    __shared__ float vL[NPB][48];
    __shared__ float vhL[NPB][3][16];
    __shared__ float FbarL[NPB][9];
    __shared__ float gateL[NPB][12];

    float (*sigL)[128] = (float (*)[128])&AL[0][0][0];

    const int t = threadIdx.x;
    const int base = blockIdx.x * NPB;
    const int nn = t >> 4, h = t & 15;
    const int n = base + nn;

    // ---- phase 0: issue count/head load first, stage v, s(->bf16 hi/lo) ----
    int e0;
    if (MODE == 2) e0 = cnt_or_head[n * NCH + (h & (NCH - 1))];   // chain count
    else           e0 = cnt_or_head[(size_t)n * NCHAIN + h];      // chain head

#pragma unroll
    for (int r = 0; r < 3; r++) vL[nn][h * 3 + r] = v[(size_t)n * 48 + h * 3 + r];
    {
        const float4* sp4 = (const float4*)(s + (size_t)n * 128 + h * 8);
        float4 s0 = sp4[0], s1 = sp4[1];
        float sv[8] = {s0.x, s0.y, s0.z, s0.w, s1.x, s1.y, s1.z, s1.w};
        s16x8 shi, slo;
#pragma unroll
        for (int j = 0; j < 8; j++) {
            short hh = f2bf(sv[j]);
            shi[j] = hh;
            slo[j] = f2bf(sv[j] - bf2f(hh));
        }
        *(s16x8*)&AL[0][nn][h * 8] = shi;
        *(s16x8*)&AL[1][nn][h * 8] = slo;
    }

    float fs[10];   // after butterfly: ALL lanes hold the node's full sums
#pragma unroll
    for (int k = 0; k < 10; k++) fs[k] = 0.f;
    float invdeg;
    {
        if (MODE == 2) {
            const int cn = e0;                       // this lane's chain count
            const int lim = cn < cap ? cn : cap;
            // lane h -> chain h&7; two lanes per chain split the slots (s step 2).
            // Each slot-step of 8 chains is a 256B contiguous run -> streaming.
            for (int sl = (h >> 3); sl < lim; sl += 2) {
                const unsigned* p = pay + (((size_t)n * cap + sl) * NCH + (h & (NCH - 1))) * 8;
                uint4 a = *(const uint4*)p;
                unsigned b = p[4];
                fs[0] += bflo(a.x); fs[1] += bfhi(a.x);
                fs[2] += bflo(a.y); fs[3] += bfhi(a.y);
                fs[4] += bflo(a.z); fs[5] += bfhi(a.z);
                fs[6] += bflo(a.w); fs[7] += bfhi(a.w);
                fs[8] += bflo(b);
            }
            if (h < NCH) {
                fs[9] = (float)cn;                   // deg contribution (once/chain)
                if (cn > cap) {                      // rare overflow walk
                    int e2 = head2[n * NCH + h];
                    while (e2 >= 0) {
                        int en = nxt[e2];
                        const float* f = frames + (size_t)e2 * 9;
                        f4u x = ((const f4u*)f)[0];
                        f4u y = ((const f4u*)f)[1];
                        float z8 = f[8];
                        fs[0] += x.a; fs[1] += x.b; fs[2] += x.c; fs[3] += x.d;
                        fs[4] += y.a; fs[5] += y.b; fs[6] += y.c; fs[7] += y.d;
                        fs[8] += z8;
                        e2 = en;
                    }
                }
            }
        } else if (MODE == 1) {
            int e = e0;
            while (e >= 0) {
                const uint4* p = (const uint4*)(pay + (size_t)e * 8);
                uint4 b = p[1];                 // {f8, nxt, 0, 0} - same sector
                uint4 a = p[0];
                int en = (int)b.y;
                fs[0] += bflo(a.x); fs[1] += bfhi(a.x);
                fs[2] += bflo(a.y); fs[3] += bfhi(a.y);
                fs[4] += bflo(a.z); fs[5] += bfhi(a.z);
                fs[6] += bflo(a.w); fs[7] += bfhi(a.w);
                fs[8] += bflo(b.x);
                fs[9] += 1.0f;
                e = en;
            }
        } else {
            int e = e0;
            while (e >= 0) {
                int en = nxt[e];
                const float* f = frames + (size_t)e * 9;
                f4u x = ((const f4u*)f)[0];
                f4u y = ((const f4u*)f)[1];
                float z8 = f[8];
                fs[0] += x.a; fs[1] += x.b; fs[2] += x.c; fs[3] += x.d;
                fs[4] += y.a; fs[5] += y.b; fs[6] += y.c; fs[7] += y.d;
                fs[8] += z8;
                fs[9] += 1.0f;
                e = en;
            }
        }
        // butterfly across the node's 16 lanes (contiguous within the wave)
#pragma unroll
        for (int m = 1; m < 16; m <<= 1) {
#pragma unroll
            for (int k = 0; k < 10; k++) fs[k] += __shfl_xor(fs[k], m);
        }
        invdeg = 1.0f / fmaxf(fs[9], 1.0f);
        if (h < 9) FbarL[nn][h] = fs[h] * invdeg;   // for phase 3
    }
    __syncthreads();

    // ---- phase 1 (fused): vh, vnorm(->A[128+h]), sh(->A[144..152]) ----
    {
        float vh0 = 0.f, vh1 = 0.f, vh2 = 0.f;
#pragma unroll
        for (int i = 0; i < 16; i++) {
            float w = W_vd[i * 16 + h];
            vh0 += vL[nn][i * 3 + 0] * w;
            vh1 += vL[nn][i * 3 + 1] * w;
            vh2 += vL[nn][i * 3 + 2] * w;
        }
        vhL[nn][0][h] = vh0; vhL[nn][1][h] = vh1; vhL[nn][2][h] = vh2;
        float vn = sqrtf(vh0 * vh0 + vh1 * vh1 + vh2 * vh2 + EPSV);
        short hh = f2bf(vn);
        AL[0][nn][128 + h] = hh;
        AL[1][nn][128 + h] = f2bf(vn - bf2f(hh));
        if (h < 9) {
            // sh[h]: c = h/3 (vdf column), i = h%3 (Fbar row)
            const int c = h / 3, i = h % 3;
            float a = 0.f;
#pragma unroll
            for (int j = 0; j < 3; j++) {
                // vdf[j*3+c] recomputed in-lane (3 dots of 16, vL same-group)
                float vd = 0.f;
#pragma unroll
                for (int ii = 0; ii < 16; ii++) vd += vL[nn][ii * 3 + j] * W_vdf[ii * 3 + c];
                a += (fs[i * 3 + j] * invdeg) * vd;   // Fbar from registers
            }
            short hs = f2bf(a);
            AL[0][nn][144 + h] = hs;
            AL[1][nn][144 + h] = f2bf(a - bf2f(hs));
        } else {
            AL[0][nn][144 + h] = 0;  // k = 153..159
            AL[1][nn][144 + h] = 0;
        }
    }
    __syncthreads();

    // ---- phase 2: C[16x128] = merged[16x160] @ W_so via split-bf16 MFMA ----
    // wave w handles o in [32w, 32w+32): two 16x16 tiles, K-loop 5x32.
    // A-frag: A[m=lane&15][k=quad*8+j] (ds_read_b128 from AL);
    // B-frag: B[k=quad*8+j][n=lane&15] (one b128 from WT[o][k] each);
    // C/D: col=lane&15, row=quad*4+reg (m89/m91/m120-verified layouts).
    {
        const int w = t >> 6;
        const int lane = t & 63;
        const int quad = lane >> 4;
        const int col = lane & 15;
        const int o0 = w * 32 + col, o1 = o0 + 16;
        f32x4 acc0 = (f32x4){0.f, 0.f, 0.f, 0.f};
        f32x4 acc1 = (f32x4){0.f, 0.f, 0.f, 0.f};
#pragma unroll
        for (int kk = 0; kk < 5; kk++) {
            const int krow = kk * 32 + quad * 8;
            s16x8 ahi = *(const s16x8*)&AL[0][col][krow];
            s16x8 alo = *(const s16x8*)&AL[1][col][krow];
            s16x8 b0h = *(const s16x8*)&WThi[o0 * 160 + krow];
            s16x8 b0l = *(const s16x8*)&WTlo[o0 * 160 + krow];
            s16x8 b1h = *(const s16x8*)&WThi[o1 * 160 + krow];
            s16x8 b1l = *(const s16x8*)&WTlo[o1 * 160 + krow];
            acc0 = __builtin_amdgcn_mfma_f32_16x16x32_bf16(ahi, b0h, acc0, 0, 0, 0);
            acc0 = __builtin_amdgcn_mfma_f32_16x16x32_bf16(ahi, b0l, acc0, 0, 0, 0);
            acc0 = __builtin_amdgcn_mfma_f32_16x16x32_bf16(alo, b0h, acc0, 0, 0, 0);
            acc1 = __builtin_amdgcn_mfma_f32_16x16x32_bf16(ahi, b1h, acc1, 0, 0, 0);
            acc1 = __builtin_amdgcn_mfma_f32_16x16x32_bf16(ahi, b1l, acc1, 0, 0, 0);
            acc1 = __builtin_amdgcn_mfma_f32_16x16x32_bf16(alo, b1h, acc1, 0, 0, 0);
        }
        __syncthreads();  // all A-frag reads of AL done -> safe to overlay sigL
        // epilogue: bias, relu -> out0, sigmoid -> sigL (overlaid on AL)
        {
            float b0 = b_so[o0], b1 = b_so[o1];
#pragma unroll
            for (int r = 0; r < 4; r++) {
                int nl = quad * 4 + r;
                float v0 = acc0[r] + b0;
                float v1 = acc1[r] + b1;
                out0[(size_t)(base + nl) * 128 + o0] = fmaxf(v0, 0.0f);
                out0[(size_t)(base + nl) * 128 + o1] = fmaxf(v1, 0.0f);
                sigL[nl][o0] = sigmoidf_(v0);
                sigL[nl][o1] = sigmoidf_(v1);
            }
        }
    }
    __syncthreads();

    // ---- gate = sigmoid(sr) @ W_vosf + b_vosf : partials + shfl butterfly ----
    {
        const float* sp = &sigL[nn][h * 8];
        float4 s0 = *(const float4*)sp;
        float4 s1 = *(const float4*)(sp + 4);
        float sv[8] = {s0.x, s0.y, s0.z, s0.w, s1.x, s1.y, s1.z, s1.w};
        float p[9];
#pragma unroll
        for (int k = 0; k < 9; k++) p[k] = 0.f;
#pragma unroll
        for (int i = 0; i < 8; i++) {
            int o = h * 8 + i;
#pragma unroll
            for (int k = 0; k < 9; k++) p[k] += sv[i] * W_vosf[o * 9 + k];
        }
#pragma unroll
        for (int m = 1; m < 16; m <<= 1) {
#pragma unroll
            for (int k = 0; k < 9; k++) p[k] += __shfl_xor(p[k], m);
        }
        if (h < 9) gateL[nn][h] = p[h] + b_vosf[h];
    }
    __syncthreads();

    // ---- phase 3: vector path ----
    {
        int o = h;  // VO index
        float gv[9];
#pragma unroll
        for (int i = 0; i < 3; i++)
#pragma unroll
            for (int kk = 0; kk < 3; kk++) {
                float a = 0.f;
#pragma unroll
                for (int j = 0; j < 3; j++) a += gateL[nn][j * 3 + i] * FbarL[nn][j * 3 + kk];
                gv[i * 3 + kk] = a;
            }
        float gvr[3];
#pragma unroll
        for (int kk = 0; kk < 3; kk++) {
            float a = 0.f;
#pragma unroll
            for (int i = 0; i < 3; i++) a += gv[i * 3 + kk] * W_vuf[i * 16 + o];
            gvr[kk] = a;
        }
        float gn2 = sqrtf(gvr[0] * gvr[0] + gvr[1] * gvr[1] + gvr[2] * gvr[2] + EPSV);
        float sg = sigmoidf_(gn2);
#pragma unroll
        for (int c = 0; c < 3; c++) {
            float a = 0.f;
#pragma unroll
            for (int h2 = 0; h2 < 16; h2++) a += vhL[nn][c][h2] * W_vu[h2 * 16 + o];
            out1[(size_t)n * 48 + o * 3 + c] = a * sg;
        }
    }
}

extern "C" void kernel_launch(void* const* d_in, const int* in_sizes, int n_in,
                              void* d_out, int out_size, void* d_ws, size_t ws_size,
                              hipStream_t stream) {
    const float* s      = (const float*)d_in[0];
    const float* v      = (const float*)d_in[1];
    const float* frames = (const float*)d_in[2];
    const float* W_vd   = (const float*)d_in[3];
    const float* W_vdf  = (const float*)d_in[4];
    const float* W_so   = (const float*)d_in[5];
    const float* b_so   = (const float*)d_in[6];
    const float* W_vu   = (const float*)d_in[7];
    const float* W_vosf = (const float*)d_in[8];
    const float* b_vosf = (const float*)d_in[9];
    const float* W_vuf  = (const float*)d_in[10];
    const int* edge_index = (const int*)d_in[11];
    // d_in[12] = node_inputs (assumed truthy, per reference)

    float* out0 = (float*)d_out;
    float* out1 = out0 + (size_t)N_NODES * 128;

    const size_t wt_b = (size_t)128 * 160 * sizeof(short);            // 40,960
    // CSR8I layout: cnt[N*8] | head2[N*8] | WThi | WTlo | nxt[E] | pay[N*cap*8*32B]
    const size_t cnt_b   = (size_t)N_NODES * NCH * sizeof(int);       // 1.6 MB
    const size_t head2_b = (size_t)N_NODES * NCH * sizeof(int);       // 1.6 MB
    const size_t nxt_b   = (size_t)N_EDGES * sizeof(int);             // 6.4 MB
    const size_t csr_base = cnt_b + head2_b + 2 * wt_b + nxt_b;       // ~9.68 MB
    long cap = 0;
    if (ws_size > csr_base)
        cap = (long)((ws_size - csr_base) / ((size_t)N_NODES * NCH * 32));
    if (cap > 16) cap = 16;

    // FAT layout (r9): head[N*16] | WThi | WTlo | pay32[E*32B]
    const size_t head_b  = (size_t)N_NODES * NCHAIN * sizeof(int);    // 3.2 MB
    const size_t fat_off = head_b + 2 * wt_b;
    const size_t fat_need = fat_off + (size_t)N_EDGES * 32;

    if (cap >= 6) {
        // ---- CSR8I path ----
        int*      cnt   = (int*)d_ws;
        int*      head2 = (int*)((char*)d_ws + cnt_b);
        short*    WThi  = (short*)((char*)d_ws + cnt_b + head2_b);
        short*    WTlo  = WThi + 128 * 160;
        int*      nxt   = (int*)((char*)d_ws + cnt_b + head2_b + 2 * wt_b);
        unsigned* pay   = (unsigned*)((char*)d_ws + csr_base);
        hipMemsetAsync(cnt, 0x00, cnt_b, stream);
        hipMemsetAsync(head2, 0xFF, head2_b, stream);
        wsplit_kernel<<<(128 * 160 + 255) / 256, 256, 0, stream>>>(W_so, WThi, WTlo);
        bucket_csr8i_kernel<<<(N_EDGES + 255) / 256, 256, 0, stream>>>(
            edge_index, frames, cnt, head2, nxt, pay, (int)cap);
        node_kernel<2><<<N_NODES / NPB, 256, 0, stream>>>(
            s, v, pay, frames, W_vd, W_vdf, WThi, WTlo, b_so, W_vu, W_vosf, b_vosf, W_vuf,
            cnt, head2, nxt, (int)cap, out0, out1);
    } else if (ws_size >= fat_need) {
        // ---- FAT path (r9-proven) ----
        int*      head = (int*)d_ws;
        short*    WThi = (short*)((char*)d_ws + head_b);
        short*    WTlo = WThi + 128 * 160;
        unsigned* pay  = (unsigned*)((char*)d_ws + fat_off);
        hipMemsetAsync(head, 0xFF, head_b, stream);
        wsplit_kernel<<<(128 * 160 + 255) / 256, 256, 0, stream>>>(W_so, WThi, WTlo);
        bucket_fat_kernel<<<(N_EDGES + 255) / 256, 256, 0, stream>>>(
            edge_index, frames, head, pay);
        node_kernel<1><<<N_NODES / NPB, 256, 0, stream>>>(
            s, v, pay, frames, W_vd, W_vdf, WThi, WTlo, b_so, W_vu, W_vosf, b_vosf, W_vuf,
            head, (const int*)nullptr, (const int*)nullptr, 0, out0, out1);
    } else {
        // ---- thin path ----
        int*   head = (int*)d_ws;
        short* WThi = (short*)((char*)d_ws + head_b);
        short* WTlo = WThi + 128 * 160;
        int*   nxt  = (int*)((char*)d_ws + fat_off);
        hipMemsetAsync(head, 0xFF, head_b, stream);
        wsplit_kernel<<<(128 * 160 + 255) / 256, 256, 0, stream>>>(W_so, WThi, WTlo);
        bucket_thin_kernel<<<(N_EDGES + 255) / 256, 256, 0, stream>>>(
            edge_index, head, nxt);
        node_kernel<0><<<N_NODES / NPB, 256, 0, stream>>>(
            s, v, (const unsigned*)nullptr, frames, W_vd, W_vdf, WThi, WTlo, b_so,
            W_vu, W_vosf, b_vosf, W_vuf, head, (const int*)nullptr, nxt, 0, out0, out1);
    }
}